// Round 9
// baseline (834.922 us; speedup 1.0000x reference)
//
#include <hip/hip_runtime.h>
#include <hip/hip_bf16.h>
#include <math.h>

#define BB 32768
#define EE 16
#define HH 128
#define OBS 8
#define NSTEP 19
#define TPB 512
#define MROWS 64
#define KT 5
// fragment-order B buffer: elem index of frag (nt, kt, T∈{hi,lo}) start
#define FBX(nt,kt,T) ((((nt)*KT+(kt))*2+(T))*512)

typedef short s16x8 __attribute__((ext_vector_type(8)));   // 8 bf16 = 4 VGPRs (MFMA A/B frag)
typedef float f32x4 __attribute__((ext_vector_type(4)));   // MFMA C/D frag

__device__ __forceinline__ float sigm(float x){ return __builtin_amdgcn_rcpf(1.0f + __expf(-x)); }
__device__ __forceinline__ float ftanh(float x){ float e = __expf(-2.f*x); return (1.f-e)*__builtin_amdgcn_rcpf(1.f+e); }
__device__ __forceinline__ unsigned int f2b(float x){
    __hip_bfloat16 h = __float2bfloat16(x);
    return (unsigned int)*reinterpret_cast<unsigned short*>(&h);
}
__device__ __forceinline__ float b2f_(unsigned int u){ return __uint_as_float(u << 16); }

// Pack W_cat = [W_ih | W_hh | bias] (K rows 0..144, pad 160) into MFMA A-frag order,
// bf16 hi+lo.  Row k=144 holds b_ih+b_hh (paired with x[144]=1.0 -> bias via MFMA).
// Frag (JT 0..31, kt 0..4): lane l elem j = W_cat[k = kt*32+(l>>4)*8+j][jg = JT*16+(l&15)],
// jg = 4*j_hidden + gate.
__global__ __launch_bounds__(256) void k_prep(
    const float* __restrict__ W_ih, const float* __restrict__ b_ih,
    const float* __restrict__ W_hh, const float* __restrict__ b_hh,
    unsigned short* __restrict__ Whi, unsigned short* __restrict__ Wlo)
{
    int idx = blockIdx.x * 256 + threadIdx.x;      // 32*5*512 = 81920
    int j    = idx & 7;
    int lane = (idx >> 3) & 63;
    int kt   = (idx >> 9) % KT;
    int JT   = idx / (KT * 512);
    int k  = kt * 32 + ((lane >> 4) << 3) + j;
    int jg = JT * 16 + (lane & 15);
    int col = (jg & 3) * HH + (jg >> 2);
    float wv = 0.f;
    if (k < EE)            wv = W_ih[col * EE + k];
    else if (k < EE + HH)  wv = W_hh[col * HH + (k - EE)];
    else if (k == EE + HH) wv = b_ih[col] + b_hh[col];
    unsigned int hi = f2b(wv);
    Whi[idx] = (unsigned short)hi;
    Wlo[idx] = (unsigned short)f2b(wv - b2f_(hi));
}

// NO occupancy attributes: R5/R6/R8 show both __launch_bounds__(,N) and
// amdgpu_waves_per_eu cap the allocator at 128 VGPRs and spill.  Peak live here
// ~130; m97 evidence says the unconstrained allocator will grant ~130-164.
__global__ void k_lstm(
    const float* __restrict__ obs,
    const float* __restrict__ W_emb, const float* __restrict__ b_emb,
    const unsigned short* __restrict__ Whi, const unsigned short* __restrict__ Wlo,
    const float* __restrict__ W_out, const float* __restrict__ b_out,
    float* __restrict__ out)
{
    __shared__ unsigned short Bbuf[4 * KT * 2 * 512];   // 40 KB, frag-order hi/lo
    __shared__ float redp[8 * MROWS * 2];               // per-wave readout partials, 4 KB
    __shared__ float wout[2 * HH];
    __shared__ float wemb[EE * 2];
    __shared__ float bemb[EE];

    const int t    = threadIdx.x;
    const int lane = t & 63;
    const int w    = t >> 6;       // wave 0..7: gate-col tiles JT = 4w..4w+3
    const int q    = lane >> 4;    // 0..3
    const int cc   = lane & 15;
    const int row0 = blockIdx.x * MROWS;

    if (t < 2 * HH) wout[t] = W_out[t];
    if (t < EE * 2) wemb[t] = W_emb[t];
    if (t < EE)     bemb[t] = b_emb[t];
    for (int i = t; i < 4 * KT * 512; i += TPB) ((unsigned int*)Bbuf)[i] = 0;

    const float bo0 = b_out[0], bo1 = b_out[1];
    const int rrow = t >> 3;       // 0..63 (tail: row)
    const int rp   = t & 7;        // tail: 8 partials / embed pairs
    const int grow = row0 + rrow;
    float pl0 = 0.f, pl1 = 0.f;

    float c16[4][4];
#pragma unroll
    for (int mt = 0; mt < 4; mt++)
#pragma unroll
        for (int nt = 0; nt < 4; nt++) c16[mt][nt] = 0.f;

    __syncthreads();

    // x[144] = 1.0 for every row (bias row; never rewritten: writeback touches k 16..143,
    // embed k 0..15).  k=144 -> kt=4, kg=2, e=0.
    if (t < MROWS) {
        int nt = t >> 4;
        Bbuf[FBX(nt, 4, 0) + (2 * 16 + (t & 15)) * 8] = 0x3F80;
    }

    // initial embed: x for step 0
    {
        float d0 = obs[(size_t)1 * BB * 2 + grow * 2 + 0] - obs[(size_t)0 * BB * 2 + grow * 2 + 0];
        float d1 = obs[(size_t)1 * BB * 2 + grow * 2 + 1] - obs[(size_t)0 * BB * 2 + grow * 2 + 1];
        int e0 = rp * 2;
        float v0 = bemb[e0]     + d0 * wemb[2 * e0]     + d1 * wemb[2 * e0 + 1]; v0 = v0 > 0.f ? v0 : 0.f;
        float v1 = bemb[e0 + 1] + d0 * wemb[2 * e0 + 2] + d1 * wemb[2 * e0 + 3]; v1 = v1 > 0.f ? v1 : 0.f;
        unsigned int h0 = f2b(v0), h1 = f2b(v1);
        unsigned int l0 = f2b(v0 - b2f_(h0)), l1 = f2b(v1 - b2f_(h1));
        int kg = rp >> 2, nt = rrow >> 4;
        int dw = (kg * 16 + (rrow & 15)) * 4 + (rp & 3);
        ((unsigned int*)Bbuf)[(FBX(nt, 0, 0) >> 1) + dw] = h0 | (h1 << 16);
        ((unsigned int*)Bbuf)[(FBX(nt, 0, 1) >> 1) + dw] = l0 | (l1 << 16);
    }
    __syncthreads();

#pragma unroll 1
    for (int s = 0; s < NSTEP; s++) {
        // ---- gates GEMM: 64 cols x 64 rows per wave, 3-term bf16 split, bias in k=144 ----
        f32x4 acc[4][4];
#pragma unroll
        for (int mt = 0; mt < 4; mt++)
#pragma unroll
            for (int nt = 0; nt < 4; nt++) acc[mt][nt] = (f32x4){0.f, 0.f, 0.f, 0.f};

#pragma unroll
        for (int kt = 0; kt < KT; kt++) {
            s16x8 bH[4], bL[4];
#pragma unroll
            for (int nt = 0; nt < 4; nt++) {
                bH[nt] = *(const s16x8*)&Bbuf[FBX(nt, kt, 0) + lane * 8];
                bL[nt] = *(const s16x8*)&Bbuf[FBX(nt, kt, 1) + lane * 8];
            }
#pragma unroll
            for (int mt = 0; mt < 4; mt++) {
                const size_t ao = ((size_t)((w * 4 + mt) * KT + kt)) * 512 + lane * 8;
                s16x8 ah = *(const s16x8*)(Whi + ao);
                s16x8 al = *(const s16x8*)(Wlo + ao);
#pragma unroll
                for (int nt = 0; nt < 4; nt++) {
                    acc[mt][nt] = __builtin_amdgcn_mfma_f32_16x16x32_bf16(ah, bH[nt], acc[mt][nt], 0, 0, 0);
                    acc[mt][nt] = __builtin_amdgcn_mfma_f32_16x16x32_bf16(al, bH[nt], acc[mt][nt], 0, 0, 0);
                    acc[mt][nt] = __builtin_amdgcn_mfma_f32_16x16x32_bf16(ah, bL[nt], acc[mt][nt], 0, 0, 0);
                }
            }
        }

        // ---- cell update: lane reg r = gate r of hidden j = (w*4+mt)*4+q ----
        float hn[4][4];
#pragma unroll
        for (int mt = 0; mt < 4; mt++)
#pragma unroll
            for (int nt = 0; nt < 4; nt++) {
                f32x4 g = acc[mt][nt];
                float cn = sigm(g[1]) * c16[mt][nt] + sigm(g[0]) * ftanh(g[2]);
                c16[mt][nt] = cn;
                hn[mt][nt] = sigm(g[3]) * ftanh(cn);
            }

        __syncthreads();   // B_A: all waves finished reading Bbuf this step

        // ---- writeback (bf16 hi/lo into frag-order Bbuf) + readout partials ----
        float p0[4] = {0.f, 0.f, 0.f, 0.f};
        float p1[4] = {0.f, 0.f, 0.f, 0.f};
#pragma unroll
        for (int mt = 0; mt < 4; mt++) {
            int j0 = (w * 4 + mt) * 4;      // this lane's j = j0 + q
            float w0r = wout[j0 + q];       // 16-lane-uniform -> LDS broadcast
            float w1r = wout[HH + j0 + q];
            int k   = EE + j0 + q;
            int kt_ = k >> 5, kg = (k >> 3) & 3, e = k & 7;
#pragma unroll
            for (int nt = 0; nt < 4; nt++) {
                float h = hn[mt][nt];
                p0[nt] += h * w0r;
                p1[nt] += h * w1r;
                unsigned int hu = f2b(h);
                unsigned int lu = f2b(h - b2f_(hu));
                unsigned int hup = __shfl_xor(hu, 16, 64);   // partner q^1 holds j0+q^1
                unsigned int lup = __shfl_xor(lu, 16, 64);
                if (!(q & 1)) {
                    int dw = (kg * 16 + cc) * 4 + (e >> 1);
                    ((unsigned int*)Bbuf)[(FBX(nt, kt_, 0) >> 1) + dw] = hu | (hup << 16);
                    ((unsigned int*)Bbuf)[(FBX(nt, kt_, 1) >> 1) + dw] = lu | (lup << 16);
                }
            }
        }
        // q-reduce readout partials -> redp[w][row]
#pragma unroll
        for (int nt = 0; nt < 4; nt++) {
            p0[nt] += __shfl_xor(p0[nt], 16, 64); p0[nt] += __shfl_xor(p0[nt], 32, 64);
            p1[nt] += __shfl_xor(p1[nt], 16, 64); p1[nt] += __shfl_xor(p1[nt], 32, 64);
        }
        if (lane < 16) {
#pragma unroll
            for (int nt = 0; nt < 4; nt++)
                ((float2*)redp)[w * MROWS + nt * 16 + cc] = make_float2(p0[nt], p1[nt]);
        }

        __syncthreads();   // B_B: h sealed in Bbuf, redp complete

        // ---- tail: sum wave partials, position, out, next-step embed ----
        {
            float r0 = 0.f, r1 = 0.f;
#pragma unroll
            for (int ww = 0; ww < 8; ww++) {
                float2 pr = ((float2*)redp)[ww * MROWS + rrow];
                r0 += pr.x; r1 += pr.y;
            }
            float base0, base1;
            if (s < OBS) {
                base0 = obs[(size_t)(s + 1) * BB * 2 + grow * 2 + 0];
                base1 = obs[(size_t)(s + 1) * BB * 2 + grow * 2 + 1];
            } else { base0 = pl0; base1 = pl1; }
            float pos0 = base0 + r0 + bo0;
            float pos1 = base1 + r1 + bo1;
            if (rp == 0) {
                out[((size_t)s * BB + grow) * 2 + 0] = pos0;
                out[((size_t)s * BB + grow) * 2 + 1] = pos1;
            }
            if (s + 1 < NSTEP) {
                float d0, d1;
                if (s + 1 < OBS) {
                    d0 = obs[(size_t)(s + 2) * BB * 2 + grow * 2 + 0] - obs[(size_t)(s + 1) * BB * 2 + grow * 2 + 0];
                    d1 = obs[(size_t)(s + 2) * BB * 2 + grow * 2 + 1] - obs[(size_t)(s + 1) * BB * 2 + grow * 2 + 1];
                } else { d0 = pos0 - pl0; d1 = pos1 - pl1; }
                int e0 = rp * 2;
                float v0 = bemb[e0]     + d0 * wemb[2 * e0]     + d1 * wemb[2 * e0 + 1]; v0 = v0 > 0.f ? v0 : 0.f;
                float v1 = bemb[e0 + 1] + d0 * wemb[2 * e0 + 2] + d1 * wemb[2 * e0 + 3]; v1 = v1 > 0.f ? v1 : 0.f;
                unsigned int h0 = f2b(v0), h1 = f2b(v1);
                unsigned int l0 = f2b(v0 - b2f_(h0)), l1 = f2b(v1 - b2f_(h1));
                int kg = rp >> 2, nt = rrow >> 4;
                int dw = (kg * 16 + (rrow & 15)) * 4 + (rp & 3);
                ((unsigned int*)Bbuf)[(FBX(nt, 0, 0) >> 1) + dw] = h0 | (h1 << 16);
                ((unsigned int*)Bbuf)[(FBX(nt, 0, 1) >> 1) + dw] = l0 | (l1 << 16);
            }
            pl0 = pos0; pl1 = pos1;
        }
        __syncthreads();   // B_C: x[s+1] sealed before next GEMM
    }
}

extern "C" void kernel_launch(void* const* d_in, const int* in_sizes, int n_in,
                              void* d_out, int out_size, void* d_ws, size_t ws_size,
                              hipStream_t stream)
{
    const float* obs   = (const float*)d_in[0];
    const float* W_emb = (const float*)d_in[1];
    const float* b_emb = (const float*)d_in[2];
    const float* W_ih  = (const float*)d_in[3];
    const float* b_ih  = (const float*)d_in[4];
    const float* W_hh  = (const float*)d_in[5];
    const float* b_hh  = (const float*)d_in[6];
    const float* W_out = (const float*)d_in[7];
    const float* b_out = (const float*)d_in[8];
    float* out = (float*)d_out;

    unsigned short* Whi = (unsigned short*)d_ws;        // 81920 bf16
    unsigned short* Wlo = Whi + 32 * KT * 512;          // 81920 bf16

    hipLaunchKernelGGL(k_prep, dim3(32 * KT * 512 / 256), dim3(256), 0, stream,
                       W_ih, b_ih, W_hh, b_hh, Whi, Wlo);

    hipLaunchKernelGGL(k_lstm, dim3(BB / MROWS), dim3(TPB), 0, stream,
                       obs, W_emb, b_emb, Whi, Wlo, W_out, b_out, out);
}

// Round 10
// 436.169 us; speedup vs baseline: 1.9142x; 1.9142x over previous
//
#include <hip/hip_runtime.h>
#include <hip/hip_bf16.h>
#include <math.h>

#define BB 32768
#define EE 16
#define HH 128
#define OBS 8
#define NSTEP 19
#define TPB 1024
#define MROWS 128
#define NKT 10          // K tiles of 16 (K=160: 16 x + 128 h + bias@144 + pad)
// fragment-order B buffer: elem index of frag (rt 0..3, kt 0..9, T∈{hi,lo})
#define FBX(rt,kt,T) ((((rt)*NKT + (kt))*2 + (T))*512)

typedef short s16x8  __attribute__((ext_vector_type(8)));    // 8 bf16 = 4 VGPRs
typedef float f32x16 __attribute__((ext_vector_type(16)));   // 32x32 MFMA C/D

__device__ __forceinline__ float sigm(float x){ return __builtin_amdgcn_rcpf(1.0f + __expf(-x)); }
__device__ __forceinline__ float ftanh(float x){ float e = __expf(-2.f*x); return (1.f-e)*__builtin_amdgcn_rcpf(1.f+e); }
__device__ __forceinline__ unsigned int f2b(float x){
    __hip_bfloat16 h = __float2bfloat16(x);
    return (unsigned int)*reinterpret_cast<unsigned short*>(&h);
}
__device__ __forceinline__ float b2f_(unsigned int u){ return __uint_as_float(u << 16); }

// Pack W_cat = [W_ih | W_hh | bias@144] into 32x32x16 MFMA A-frag order, bf16 hi+lo.
// Frag (JT 0..15, kt 0..9): lane l elem j = W_cat[k = kt*16+(l>>5)*8+j][jg = JT*32+(l&31)],
// jg = 4*j_hidden + gate.
__global__ __launch_bounds__(256) void k_prep(
    const float* __restrict__ W_ih, const float* __restrict__ b_ih,
    const float* __restrict__ W_hh, const float* __restrict__ b_hh,
    unsigned short* __restrict__ Whi, unsigned short* __restrict__ Wlo)
{
    int idx = blockIdx.x * 256 + threadIdx.x;      // 16*10*512 = 81920
    int j    = idx & 7;
    int lane = (idx >> 3) & 63;
    int kt   = (idx >> 9) % NKT;
    int JT   = idx / (NKT * 512);
    int k  = kt * 16 + ((lane >> 5) << 3) + j;
    int jg = JT * 32 + (lane & 31);
    int col = (jg & 3) * HH + (jg >> 2);
    float wv = 0.f;
    if (k < EE)            wv = W_ih[col * EE + k];
    else if (k < EE + HH)  wv = W_hh[col * HH + (k - EE)];
    else if (k == EE + HH) wv = b_ih[col] + b_hh[col];
    unsigned int hi = f2b(wv);
    Whi[idx] = (unsigned short)hi;
    Wlo[idx] = (unsigned short)f2b(wv - b2f_(hi));
}

// R7's exact (and only spill-free) occupancy recipe: TPB=1024 block = whole CU,
// flat_work_group_size + waves_per_eu(4,4) -> 128-reg unified budget, acc in AGPRs.
__global__ __attribute__((amdgpu_flat_work_group_size(TPB, TPB)))
           __attribute__((amdgpu_waves_per_eu(4, 4)))
void k_lstm(
    const float* __restrict__ obs,
    const float* __restrict__ W_emb, const float* __restrict__ b_emb,
    const unsigned short* __restrict__ Whi, const unsigned short* __restrict__ Wlo,
    const float* __restrict__ W_out, const float* __restrict__ b_out,
    float* __restrict__ out)
{
    __shared__ unsigned short Bbuf[4 * NKT * 2 * 512];   // 80 KB, frag-order hi/lo
    __shared__ float2 redp2[8 * MROWS];                  // 8 KB readout partials
    __shared__ float wout[2 * HH];
    __shared__ float wemb[EE * 2];
    __shared__ float bemb[EE];

    const int t    = threadIdx.x;
    const int lane = t & 63;
    const int w    = t >> 6;       // wave 0..15
    const int cw   = w & 7;        // col group: JT = cw*2 + ct (64 gate-cols)
    const int rtg  = w >> 3;       // row group: rt = rtg*2 + rr (64 rows)
    const int q5   = lane >> 5;
    const int rowl = lane & 31;
    const int row0 = blockIdx.x * MROWS;

    if (t < 2 * HH) wout[t] = W_out[t];
    if (t < EE * 2) wemb[t] = W_emb[t];
    if (t < EE)     bemb[t] = b_emb[t];
    for (int i = t; i < 4 * NKT * 512; i += TPB) ((unsigned int*)Bbuf)[i] = 0;

    const float bo0 = b_out[0], bo1 = b_out[1];
    const int rrow = t >> 3;       // tail row 0..127
    const int rp   = t & 7;        // tail partial slot
    const int grow = row0 + rrow;
    float pl0 = 0.f, pl1 = 0.f;

    float c_[2][2][4];
#pragma unroll
    for (int a = 0; a < 2; a++)
#pragma unroll
        for (int b = 0; b < 2; b++)
#pragma unroll
            for (int r = 0; r < 4; r++) c_[a][b][r] = 0.f;

    __syncthreads();

    // bias row k=144 -> kt=9, sub=0, e=0: x[144] = 1.0 (never rewritten)
    if (t < MROWS)
        Bbuf[FBX(t >> 5, 9, 0) + (t & 31) * 8] = 0x3F80;

    // initial embed x[0]
    if (rp < 2) {
        float d0 = obs[(size_t)1 * BB * 2 + grow * 2 + 0] - obs[(size_t)0 * BB * 2 + grow * 2 + 0];
        float d1 = obs[(size_t)1 * BB * 2 + grow * 2 + 1] - obs[(size_t)0 * BB * 2 + grow * 2 + 1];
        uint4 hw, lw;
#pragma unroll
        for (int d = 0; d < 4; d++) {
            int e = rp * 8 + 2 * d;
            float v0 = bemb[e]     + d0 * wemb[2 * e]     + d1 * wemb[2 * e + 1]; v0 = v0 > 0.f ? v0 : 0.f;
            float v1 = bemb[e + 1] + d0 * wemb[2 * e + 2] + d1 * wemb[2 * e + 3]; v1 = v1 > 0.f ? v1 : 0.f;
            unsigned int h0 = f2b(v0), h1 = f2b(v1);
            unsigned int l0 = f2b(v0 - b2f_(h0)), l1 = f2b(v1 - b2f_(h1));
            ((unsigned int*)&hw)[d] = h0 | (h1 << 16);
            ((unsigned int*)&lw)[d] = l0 | (l1 << 16);
        }
        unsigned int* bp = (unsigned int*)Bbuf;
        int dwb = (FBX(rrow >> 5, 0, 0) >> 1) + (rp * 32 + (rrow & 31)) * 4;
        *(uint4*)&bp[dwb]       = hw;
        *(uint4*)&bp[dwb + 256] = lw;   // lo frag = +512 elems = +256 dwords
    }
    __syncthreads();

#pragma unroll 1
    for (int s = 0; s < NSTEP; s++) {
        // ---- gates GEMM: 64 cols x 64 rows per wave, 32x32x16, 3-term bf16 split ----
        f32x16 acc[2][2];   // [ct][rr]
#pragma unroll
        for (int ct = 0; ct < 2; ct++)
#pragma unroll
            for (int rr = 0; rr < 2; rr++)
#pragma unroll
                for (int e = 0; e < 16; e++) acc[ct][rr][e] = 0.f;

#pragma unroll 2
        for (int kt = 0; kt < NKT; kt++) {
            const int rt0 = rtg * 2, rt1 = rt0 + 1;
            s16x8 bH0 = *(const s16x8*)&Bbuf[FBX(rt0, kt, 0) + lane * 8];
            s16x8 bH1 = *(const s16x8*)&Bbuf[FBX(rt1, kt, 0) + lane * 8];
            s16x8 bL0 = *(const s16x8*)&Bbuf[FBX(rt0, kt, 1) + lane * 8];
            s16x8 bL1 = *(const s16x8*)&Bbuf[FBX(rt1, kt, 1) + lane * 8];
#pragma unroll
            for (int ct = 0; ct < 2; ct++) {
                const size_t ao = ((size_t)((cw * 2 + ct) * NKT + kt)) * 512 + lane * 8;
                s16x8 ah = *(const s16x8*)(Whi + ao);
                s16x8 al = *(const s16x8*)(Wlo + ao);
                acc[ct][0] = __builtin_amdgcn_mfma_f32_32x32x16_bf16(ah, bH0, acc[ct][0], 0, 0, 0);
                acc[ct][1] = __builtin_amdgcn_mfma_f32_32x32x16_bf16(ah, bH1, acc[ct][1], 0, 0, 0);
                acc[ct][0] = __builtin_amdgcn_mfma_f32_32x32x16_bf16(al, bH0, acc[ct][0], 0, 0, 0);
                acc[ct][1] = __builtin_amdgcn_mfma_f32_32x32x16_bf16(al, bH1, acc[ct][1], 0, 0, 0);
                acc[ct][0] = __builtin_amdgcn_mfma_f32_32x32x16_bf16(ah, bL0, acc[ct][0], 0, 0, 0);
                acc[ct][1] = __builtin_amdgcn_mfma_f32_32x32x16_bf16(ah, bL1, acc[ct][1], 0, 0, 0);
            }
        }

        __syncthreads();   // B_A: all waves done reading Bbuf this step

        // ---- cell update (C-layout: lane reg r2*4+g = gate g of j = JT*8+2*r2+q5,
        //      row = rt*32 + rowl) + packed b128 writeback + readout partials ----
        float p0[2] = {0.f, 0.f}, p1[2] = {0.f, 0.f};
#pragma unroll
        for (int ct = 0; ct < 2; ct++) {
            const int JT = cw * 2 + ct;
#pragma unroll
            for (int rr = 0; rr < 2; rr++) {
                const int rt = rtg * 2 + rr;
                uint4 hw, lw;
#pragma unroll
                for (int r2 = 0; r2 < 4; r2++) {
                    float gi = acc[ct][rr][r2 * 4 + 0];
                    float gf = acc[ct][rr][r2 * 4 + 1];
                    float gg = acc[ct][rr][r2 * 4 + 2];
                    float go = acc[ct][rr][r2 * 4 + 3];
                    float cn = sigm(gf) * c_[ct][rr][r2] + sigm(gi) * ftanh(gg);
                    c_[ct][rr][r2] = cn;
                    float h = sigm(go) * ftanh(cn);
                    int jj = JT * 8 + 2 * r2 + q5;
                    p0[rr] += h * wout[jj];
                    p1[rr] += h * wout[HH + jj];
                    unsigned int hu = f2b(h);
                    unsigned int lu = f2b(h - b2f_(hu));
                    unsigned int hup = __shfl_xor(hu, 32, 64);   // partner holds e=2*r2+1
                    unsigned int lup = __shfl_xor(lu, 32, 64);
                    ((unsigned int*)&hw)[r2] = hu | (hup << 16);
                    ((unsigned int*)&lw)[r2] = lu | (lup << 16);
                }
                if (q5 == 0) {   // k = 16+16*cw+8*ct+2*r2+q5 -> kt=1+cw, sub=ct
                    unsigned int* bp = (unsigned int*)Bbuf;
                    int dwb = (FBX(rt, 1 + cw, 0) >> 1) + (ct * 32 + rowl) * 4;
                    *(uint4*)&bp[dwb]       = hw;
                    *(uint4*)&bp[dwb + 256] = lw;
                }
            }
        }
#pragma unroll
        for (int rr = 0; rr < 2; rr++) {
            p0[rr] += __shfl_xor(p0[rr], 32, 64);
            p1[rr] += __shfl_xor(p1[rr], 32, 64);
        }
        if (lane < 32) {
            redp2[cw * MROWS + (rtg * 2 + 0) * 32 + rowl] = make_float2(p0[0], p1[0]);
            redp2[cw * MROWS + (rtg * 2 + 1) * 32 + rowl] = make_float2(p0[1], p1[1]);
        }

        __syncthreads();   // B_B: h frags + redp sealed

        // ---- tail: reduce partials, position, out, next-step embed ----
        {
            float2 pr = redp2[rp * MROWS + rrow];
            float r0 = pr.x, r1 = pr.y;
#pragma unroll
            for (int m = 1; m < 8; m <<= 1) {
                r0 += __shfl_xor(r0, m, 64);
                r1 += __shfl_xor(r1, m, 64);
            }
            float base0, base1;
            if (s < OBS) {
                base0 = obs[(size_t)(s + 1) * BB * 2 + grow * 2 + 0];
                base1 = obs[(size_t)(s + 1) * BB * 2 + grow * 2 + 1];
            } else { base0 = pl0; base1 = pl1; }
            float pos0 = base0 + r0 + bo0;
            float pos1 = base1 + r1 + bo1;
            if (rp == 0)
                *(float2*)&out[((size_t)s * BB + grow) * 2] = make_float2(pos0, pos1);
            if (s + 1 < NSTEP && rp < 2) {
                float d0, d1;
                if (s + 1 < OBS) {
                    d0 = obs[(size_t)(s + 2) * BB * 2 + grow * 2 + 0] - obs[(size_t)(s + 1) * BB * 2 + grow * 2 + 0];
                    d1 = obs[(size_t)(s + 2) * BB * 2 + grow * 2 + 1] - obs[(size_t)(s + 1) * BB * 2 + grow * 2 + 1];
                } else { d0 = pos0 - pl0; d1 = pos1 - pl1; }
                uint4 hw, lw;
#pragma unroll
                for (int d = 0; d < 4; d++) {
                    int e = rp * 8 + 2 * d;
                    float v0 = bemb[e]     + d0 * wemb[2 * e]     + d1 * wemb[2 * e + 1]; v0 = v0 > 0.f ? v0 : 0.f;
                    float v1 = bemb[e + 1] + d0 * wemb[2 * e + 2] + d1 * wemb[2 * e + 3]; v1 = v1 > 0.f ? v1 : 0.f;
                    unsigned int h0 = f2b(v0), h1 = f2b(v1);
                    unsigned int l0 = f2b(v0 - b2f_(h0)), l1 = f2b(v1 - b2f_(h1));
                    ((unsigned int*)&hw)[d] = h0 | (h1 << 16);
                    ((unsigned int*)&lw)[d] = l0 | (l1 << 16);
                }
                unsigned int* bp = (unsigned int*)Bbuf;
                int dwb = (FBX(rrow >> 5, 0, 0) >> 1) + (rp * 32 + (rrow & 31)) * 4;
                *(uint4*)&bp[dwb]       = hw;
                *(uint4*)&bp[dwb + 256] = lw;
            }
            pl0 = pos0; pl1 = pos1;
        }
        __syncthreads();   // B_C: x[s+1] sealed before next GEMM
    }
}

extern "C" void kernel_launch(void* const* d_in, const int* in_sizes, int n_in,
                              void* d_out, int out_size, void* d_ws, size_t ws_size,
                              hipStream_t stream)
{
    const float* obs   = (const float*)d_in[0];
    const float* W_emb = (const float*)d_in[1];
    const float* b_emb = (const float*)d_in[2];
    const float* W_ih  = (const float*)d_in[3];
    const float* b_ih  = (const float*)d_in[4];
    const float* W_hh  = (const float*)d_in[5];
    const float* b_hh  = (const float*)d_in[6];
    const float* W_out = (const float*)d_in[7];
    const float* b_out = (const float*)d_in[8];
    float* out = (float*)d_out;

    unsigned short* Whi = (unsigned short*)d_ws;        // 81920 bf16
    unsigned short* Wlo = Whi + 16 * NKT * 512;         // 81920 bf16

    hipLaunchKernelGGL(k_prep, dim3(16 * NKT * 512 / 256), dim3(256), 0, stream,
                       W_ih, b_ih, W_hh, b_hh, Whi, Wlo);

    hipLaunchKernelGGL(k_lstm, dim3(BB / MROWS), dim3(TPB), 0, stream,
                       obs, W_emb, b_emb, Whi, Wlo, W_out, b_out, out);
}

// Round 11
// 390.772 us; speedup vs baseline: 2.1366x; 1.1162x over previous
//
#include <hip/hip_runtime.h>
#include <hip/hip_bf16.h>
#include <math.h>

#define BB 32768
#define EE 16
#define HH 128
#define OBS 8
#define NSTEP 19
#define TPB 512
#define MROWS 64
#define NKT 10          // K tiles of 16 (K=160: 16 x + 128 h + bias@144 + pad)
// fragment-order B buffer: elem index of frag (rt 0..1, kt 0..9, T∈{hi,lo})
#define FBX(rt,kt,T) ((((rt)*NKT + (kt))*2 + (T))*512)

typedef short s16x8  __attribute__((ext_vector_type(8)));    // 8 bf16 = 4 VGPRs
typedef float f32x16 __attribute__((ext_vector_type(16)));   // 32x32 MFMA C/D

__device__ __forceinline__ float sigm(float x){ return __builtin_amdgcn_rcpf(1.0f + __expf(-x)); }
__device__ __forceinline__ float ftanh(float x){ float e = __expf(-2.f*x); return (1.f-e)*__builtin_amdgcn_rcpf(1.f+e); }
__device__ __forceinline__ unsigned int f2b(float x){
    __hip_bfloat16 h = __float2bfloat16(x);
    return (unsigned int)*reinterpret_cast<unsigned short*>(&h);
}
__device__ __forceinline__ float b2f_(unsigned int u){ return __uint_as_float(u << 16); }
// cheap hi/lo split: hi = truncate(x), lo = truncate(x - hi).  ~4 VALU vs ~10+ for RNE
// pairs; |err| <= 2^-16 rel (lo captures hi's trunc error exactly).
__device__ __forceinline__ void splitT(float x, unsigned int& hi, unsigned int& lo){
    unsigned int u = __float_as_uint(x);
    hi = u >> 16;
    float r = x - __uint_as_float(u & 0xFFFF0000u);
    lo = __float_as_uint(r) >> 16;
}

// Pack W_cat = [W_ih | W_hh | bias@144] into 32x32x16 MFMA A-frag order, bf16 hi+lo
// (RNE split here -- runs once).  Frag (JT 0..15, kt 0..9): lane l elem j =
// W_cat[k = kt*16+(l>>5)*8+j][jg = JT*32+(l&31)], jg = 4*j_hidden + gate.
__global__ __launch_bounds__(256) void k_prep(
    const float* __restrict__ W_ih, const float* __restrict__ b_ih,
    const float* __restrict__ W_hh, const float* __restrict__ b_hh,
    unsigned short* __restrict__ Whi, unsigned short* __restrict__ Wlo)
{
    int idx = blockIdx.x * 256 + threadIdx.x;      // 16*10*512 = 81920
    int j    = idx & 7;
    int lane = (idx >> 3) & 63;
    int kt   = (idx >> 9) % NKT;
    int JT   = idx / (NKT * 512);
    int k  = kt * 16 + ((lane >> 5) << 3) + j;
    int jg = JT * 32 + (lane & 31);
    int col = (jg & 3) * HH + (jg >> 2);
    float wv = 0.f;
    if (k < EE)            wv = W_ih[col * EE + k];
    else if (k < EE + HH)  wv = W_hh[col * HH + (k - EE)];
    else if (k == EE + HH) wv = b_ih[col] + b_hh[col];
    unsigned int hi = f2b(wv);
    Whi[idx] = (unsigned short)hi;
    Wlo[idx] = (unsigned short)f2b(wv - b2f_(hi));
}

// TPB=512 / MROWS=64: LDS ~46 KB and 64V+64A regs -> TWO resident blocks/CU
// (R10's 90 KB forced 1 block/CU; its 3 barriers/step then stalled the whole CU).
__global__ __attribute__((amdgpu_flat_work_group_size(TPB, TPB)))
           __attribute__((amdgpu_waves_per_eu(4, 4)))
void k_lstm(
    const float* __restrict__ obs,
    const float* __restrict__ W_emb, const float* __restrict__ b_emb,
    const unsigned short* __restrict__ Whi, const unsigned short* __restrict__ Wlo,
    const float* __restrict__ W_out, const float* __restrict__ b_out,
    float* __restrict__ out)
{
    __shared__ unsigned short Bbuf[2 * NKT * 2 * 512];   // 40 KB, frag-order hi/lo
    __shared__ float2 redp2[8 * MROWS];                  // 4 KB readout partials
    __shared__ float wout[2 * HH];
    __shared__ float wemb[EE * 2];
    __shared__ float bemb[EE];

    const int t    = threadIdx.x;
    const int lane = t & 63;
    const int cw   = t >> 6;       // wave 0..7: col tiles JT = cw*2 + ct (64 gate-cols)
    const int q5   = lane >> 5;
    const int rowl = lane & 31;
    const int row0 = blockIdx.x * MROWS;

    if (t < 2 * HH) wout[t] = W_out[t];
    if (t < EE * 2) wemb[t] = W_emb[t];
    if (t < EE)     bemb[t] = b_emb[t];
    for (int i = t; i < 2 * NKT * 512; i += TPB) ((unsigned int*)Bbuf)[i] = 0;

    const float bo0 = b_out[0], bo1 = b_out[1];
    const int rrow = t >> 3;       // tail row 0..63
    const int rp   = t & 7;        // tail partial slot
    const int grow = row0 + rrow;
    float pl0 = 0.f, pl1 = 0.f;

    float c_[2][2][4];             // [ct][rt][r2]
#pragma unroll
    for (int a = 0; a < 2; a++)
#pragma unroll
        for (int b = 0; b < 2; b++)
#pragma unroll
            for (int r = 0; r < 4; r++) c_[a][b][r] = 0.f;

    __syncthreads();

    // bias row k=144 -> kt=9, sub=0, elem j=0: x[144] = 1.0 (never rewritten)
    if (t < MROWS)
        Bbuf[FBX(t >> 5, 9, 0) + (t & 31) * 8] = 0x3F80;

    // initial embed x[0]
    if (rp < 2) {
        float d0 = obs[(size_t)1 * BB * 2 + grow * 2 + 0] - obs[(size_t)0 * BB * 2 + grow * 2 + 0];
        float d1 = obs[(size_t)1 * BB * 2 + grow * 2 + 1] - obs[(size_t)0 * BB * 2 + grow * 2 + 1];
        uint4 hw, lw;
#pragma unroll
        for (int d = 0; d < 4; d++) {
            int e = rp * 8 + 2 * d;
            float v0 = bemb[e]     + d0 * wemb[2 * e]     + d1 * wemb[2 * e + 1]; v0 = v0 > 0.f ? v0 : 0.f;
            float v1 = bemb[e + 1] + d0 * wemb[2 * e + 2] + d1 * wemb[2 * e + 3]; v1 = v1 > 0.f ? v1 : 0.f;
            unsigned int h0, l0, h1, l1;
            splitT(v0, h0, l0); splitT(v1, h1, l1);
            ((unsigned int*)&hw)[d] = h0 | (h1 << 16);
            ((unsigned int*)&lw)[d] = l0 | (l1 << 16);
        }
        unsigned int* bp = (unsigned int*)Bbuf;
        int dwb = (FBX(rrow >> 5, 0, 0) >> 1) + (rp * 32 + (rrow & 31)) * 4;
        *(uint4*)&bp[dwb]       = hw;
        *(uint4*)&bp[dwb + 256] = lw;   // lo frag = +512 elems = +256 dwords
    }
    __syncthreads();

#pragma unroll 1
    for (int s = 0; s < NSTEP; s++) {
        // ---- gates GEMM: 64 cols x 64 rows per wave, 32x32x16, 3-term bf16 split ----
        f32x16 acc[2][2];   // [ct][rt]
#pragma unroll
        for (int ct = 0; ct < 2; ct++)
#pragma unroll
            for (int rt = 0; rt < 2; rt++)
#pragma unroll
                for (int e = 0; e < 16; e++) acc[ct][rt][e] = 0.f;

#pragma unroll 2
        for (int kt = 0; kt < NKT; kt++) {
            s16x8 bH0 = *(const s16x8*)&Bbuf[FBX(0, kt, 0) + lane * 8];
            s16x8 bH1 = *(const s16x8*)&Bbuf[FBX(1, kt, 0) + lane * 8];
            s16x8 bL0 = *(const s16x8*)&Bbuf[FBX(0, kt, 1) + lane * 8];
            s16x8 bL1 = *(const s16x8*)&Bbuf[FBX(1, kt, 1) + lane * 8];
#pragma unroll
            for (int ct = 0; ct < 2; ct++) {
                const size_t ao = ((size_t)((cw * 2 + ct) * NKT + kt)) * 512 + lane * 8;
                s16x8 ah = *(const s16x8*)(Whi + ao);
                s16x8 al = *(const s16x8*)(Wlo + ao);
                acc[ct][0] = __builtin_amdgcn_mfma_f32_32x32x16_bf16(ah, bH0, acc[ct][0], 0, 0, 0);
                acc[ct][1] = __builtin_amdgcn_mfma_f32_32x32x16_bf16(ah, bH1, acc[ct][1], 0, 0, 0);
                acc[ct][0] = __builtin_amdgcn_mfma_f32_32x32x16_bf16(al, bH0, acc[ct][0], 0, 0, 0);
                acc[ct][1] = __builtin_amdgcn_mfma_f32_32x32x16_bf16(al, bH1, acc[ct][1], 0, 0, 0);
                acc[ct][0] = __builtin_amdgcn_mfma_f32_32x32x16_bf16(ah, bL0, acc[ct][0], 0, 0, 0);
                acc[ct][1] = __builtin_amdgcn_mfma_f32_32x32x16_bf16(ah, bL1, acc[ct][1], 0, 0, 0);
            }
        }

        __syncthreads();   // B_A: all waves done reading Bbuf this step

        // ---- cell update (C-layout: reg r2*4+g = gate g of j = JT*8+2*r2+q5,
        //      row = rt*32 + rowl) + packed b128 writeback + readout partials ----
        float p0[2] = {0.f, 0.f}, p1[2] = {0.f, 0.f};
#pragma unroll
        for (int ct = 0; ct < 2; ct++) {
            const int JT = cw * 2 + ct;
#pragma unroll
            for (int rt = 0; rt < 2; rt++) {
                uint4 hw, lw;
#pragma unroll
                for (int r2 = 0; r2 < 4; r2++) {
                    float gi = acc[ct][rt][r2 * 4 + 0];
                    float gf = acc[ct][rt][r2 * 4 + 1];
                    float gg = acc[ct][rt][r2 * 4 + 2];
                    float go = acc[ct][rt][r2 * 4 + 3];
                    float cn = sigm(gf) * c_[ct][rt][r2] + sigm(gi) * ftanh(gg);
                    c_[ct][rt][r2] = cn;
                    float h = sigm(go) * ftanh(cn);
                    int jj = JT * 8 + 2 * r2 + q5;
                    p0[rt] += h * wout[jj];
                    p1[rt] += h * wout[HH + jj];
                    unsigned int hu, lu;
                    splitT(h, hu, lu);
                    unsigned int hup = __shfl_xor(hu, 32, 64);   // partner holds e=2*r2+1
                    unsigned int lup = __shfl_xor(lu, 32, 64);
                    ((unsigned int*)&hw)[r2] = hu | (hup << 16);
                    ((unsigned int*)&lw)[r2] = lu | (lup << 16);
                }
                if (q5 == 0) {   // k = 16+16*cw+8*ct+2*r2+q5 -> kt=1+cw, sub=ct
                    unsigned int* bp = (unsigned int*)Bbuf;
                    int dwb = (FBX(rt, 1 + cw, 0) >> 1) + (ct * 32 + rowl) * 4;
                    *(uint4*)&bp[dwb]       = hw;
                    *(uint4*)&bp[dwb + 256] = lw;
                }
            }
        }
#pragma unroll
        for (int rt = 0; rt < 2; rt++) {
            p0[rt] += __shfl_xor(p0[rt], 32, 64);
            p1[rt] += __shfl_xor(p1[rt], 32, 64);
        }
        if (lane < 32) {
            redp2[cw * MROWS + 0 * 32 + rowl] = make_float2(p0[0], p1[0]);
            redp2[cw * MROWS + 1 * 32 + rowl] = make_float2(p0[1], p1[1]);
        }

        __syncthreads();   // B_B: h frags + redp sealed

        // ---- tail: reduce partials, position, out, next-step embed ----
        {
            float2 pr = redp2[rp * MROWS + rrow];
            float r0 = pr.x, r1 = pr.y;
#pragma unroll
            for (int m = 1; m < 8; m <<= 1) {
                r0 += __shfl_xor(r0, m, 64);
                r1 += __shfl_xor(r1, m, 64);
            }
            float base0, base1;
            if (s < OBS) {
                base0 = obs[(size_t)(s + 1) * BB * 2 + grow * 2 + 0];
                base1 = obs[(size_t)(s + 1) * BB * 2 + grow * 2 + 1];
            } else { base0 = pl0; base1 = pl1; }
            float pos0 = base0 + r0 + bo0;
            float pos1 = base1 + r1 + bo1;
            if (rp == 0)
                *(float2*)&out[((size_t)s * BB + grow) * 2] = make_float2(pos0, pos1);
            if (s + 1 < NSTEP && rp < 2) {
                float d0, d1;
                if (s + 1 < OBS) {
                    d0 = obs[(size_t)(s + 2) * BB * 2 + grow * 2 + 0] - obs[(size_t)(s + 1) * BB * 2 + grow * 2 + 0];
                    d1 = obs[(size_t)(s + 2) * BB * 2 + grow * 2 + 1] - obs[(size_t)(s + 1) * BB * 2 + grow * 2 + 1];
                } else { d0 = pos0 - pl0; d1 = pos1 - pl1; }
                uint4 hw, lw;
#pragma unroll
                for (int d = 0; d < 4; d++) {
                    int e = rp * 8 + 2 * d;
                    float v0 = bemb[e]     + d0 * wemb[2 * e]     + d1 * wemb[2 * e + 1]; v0 = v0 > 0.f ? v0 : 0.f;
                    float v1 = bemb[e + 1] + d0 * wemb[2 * e + 2] + d1 * wemb[2 * e + 3]; v1 = v1 > 0.f ? v1 : 0.f;
                    unsigned int h0, l0, h1, l1;
                    splitT(v0, h0, l0); splitT(v1, h1, l1);
                    ((unsigned int*)&hw)[d] = h0 | (h1 << 16);
                    ((unsigned int*)&lw)[d] = l0 | (l1 << 16);
                }
                unsigned int* bp = (unsigned int*)Bbuf;
                int dwb = (FBX(rrow >> 5, 0, 0) >> 1) + (rp * 32 + (rrow & 31)) * 4;
                *(uint4*)&bp[dwb]       = hw;
                *(uint4*)&bp[dwb + 256] = lw;
            }
            pl0 = pos0; pl1 = pos1;
        }
        __syncthreads();   // B_C: x[s+1] sealed before next GEMM
    }
}

extern "C" void kernel_launch(void* const* d_in, const int* in_sizes, int n_in,
                              void* d_out, int out_size, void* d_ws, size_t ws_size,
                              hipStream_t stream)
{
    const float* obs   = (const float*)d_in[0];
    const float* W_emb = (const float*)d_in[1];
    const float* b_emb = (const float*)d_in[2];
    const float* W_ih  = (const float*)d_in[3];
    const float* b_ih  = (const float*)d_in[4];
    const float* W_hh  = (const float*)d_in[5];
    const float* b_hh  = (const float*)d_in[6];
    const float* W_out = (const float*)d_in[7];
    const float* b_out = (const float*)d_in[8];
    float* out = (float*)d_out;

    unsigned short* Whi = (unsigned short*)d_ws;        // 81920 bf16
    unsigned short* Wlo = Whi + 16 * NKT * 512;         // 81920 bf16

    hipLaunchKernelGGL(k_prep, dim3(16 * NKT * 512 / 256), dim3(256), 0, stream,
                       W_ih, b_ih, W_hh, b_hh, Whi, Wlo);

    hipLaunchKernelGGL(k_lstm, dim3(BB / MROWS), dim3(TPB), 0, stream,
                       obs, W_emb, b_emb, Whi, Wlo, W_out, b_out, out);
}